// Round 5
// baseline (118.387 us; speedup 1.0000x reference)
//
#include <hip/hip_runtime.h>
#include <math.h>

#define BLOCK 256
#define HP 8             // float2 packs per thread -> PPT = 16 owned points
#define PPT (2 * HP)
#define NCHUNK 64        // opposing dimension split into chunks of 128
#define FBLOCKS 256      // finalize blocks

typedef float v2f __attribute__((ext_vector_type(2)));

// Phase 1: for each owned point p (register-resident, packed 2/float2), scan a
// chunk of the opposing set (staged in LDS, pre-scaled to (-2x,-2y,-2z,|b|^2))
// and record the chunk-partial min of (b^2 - 2 a.b) via a PLAIN store:
// part[dir][chunk][point]. a^2 added in finalize.
//
// Inner math uses v_pk_fma_f32 (VOP3P packed fp32): per (2 A x 2 j) =
// 6 pk_fma + 2 v_min3 = 2.0 instr/pair (vs 3.5 scalar). b-component splats
// should lower to op_sel (no v_mov). PPT=16 keeps VALU ahead of the LDS pipe
// (128 SIMD-cyc VALU vs 96 LDS-cyc per CU per 2j).
__global__ __launch_bounds__(BLOCK) void chamfer_min_kernel(
    const float* __restrict__ arr1, const float* __restrict__ arr2,
    int Bb, int N, int M, int nchunk,
    float* __restrict__ part, float* __restrict__ out)
{
    const int dir = blockIdx.z;
    const int nA = dir ? M : N;
    const int nB = dir ? N : M;
    const float* Aptr = dir ? arr2 : arr1;   // owned points
    const float* Bptr = dir ? arr1 : arr2;   // scanned points
    const int BN = Bb * N;
    const int nOwn = Bb * nA;
    float* pbase = part + (dir ? (size_t)nchunk * BN : 0);

    // Zero the output accumulator exactly once (finalize is a later dispatch).
    if (blockIdx.x == 0 && blockIdx.y == 0 && blockIdx.z == 0 && threadIdx.x == 0)
        out[0] = 0.0f;

    const int clen = nB / nchunk;
    const int a_start = blockIdx.x * (BLOCK * PPT);  // flat index into [nOwn)
    const int batch   = a_start / nA;                // 4096 | 8192 -> exact

    extern __shared__ float4 sb[];                   // clen entries

    // Stage chunk of scanned points, pre-scaled: (-2x, -2y, -2z, |b|^2)
    {
        const float* bbase = Bptr + ((size_t)batch * nB + (size_t)blockIdx.y * clen) * 3;
        for (int i = threadIdx.x; i < clen; i += BLOCK) {
            float x = bbase[i * 3 + 0];
            float y = bbase[i * 3 + 1];
            float z = bbase[i * 3 + 2];
            sb[i] = make_float4(-2.0f * x, -2.0f * y, -2.0f * z,
                                __builtin_fmaf(x, x, __builtin_fmaf(y, y, z * z)));
        }
    }
    __syncthreads();

    // Owned points in register packs: pack p holds points (2p, 2p+1) in .x/.y
    v2f axp[HP], ayp[HP], azp[HP], mnp[HP];
    const float* abase = Aptr + (size_t)a_start * 3;
#pragma unroll
    for (int p = 0; p < HP; ++p) {
        int i0 = threadIdx.x + (2 * p) * BLOCK;
        int i1 = threadIdx.x + (2 * p + 1) * BLOCK;
        axp[p] = (v2f){abase[i0 * 3 + 0], abase[i1 * 3 + 0]};
        ayp[p] = (v2f){abase[i0 * 3 + 1], abase[i1 * 3 + 1]};
        azp[p] = (v2f){abase[i0 * 3 + 2], abase[i1 * 3 + 2]};
        mnp[p] = (v2f){__builtin_inff(), __builtin_inff()};
    }

    // Inner scan, 2 opposing points per step.
#pragma unroll 2
    for (int j = 0; j < clen; j += 2) {
        float4 b0 = sb[j];
        float4 b1 = sb[j + 1];
        v2f b0x = b0.x, b0y = b0.y, b0z = b0.z, b0w = b0.w;  // splats
        v2f b1x = b1.x, b1y = b1.y, b1z = b1.z, b1w = b1.w;
#pragma unroll
        for (int p = 0; p < HP; ++p) {
            v2f u0 = __builtin_elementwise_fma(b0x, axp[p],
                     __builtin_elementwise_fma(b0y, ayp[p],
                     __builtin_elementwise_fma(b0z, azp[p], b0w)));
            v2f u1 = __builtin_elementwise_fma(b1x, axp[p],
                     __builtin_elementwise_fma(b1y, ayp[p],
                     __builtin_elementwise_fma(b1z, azp[p], b1w)));
            // scalar min3 folds: min(min(u0,u1), mn) -> v_min3_f32
            mnp[p].x = fminf(mnp[p].x, fminf(u0.x, u1.x));
            mnp[p].y = fminf(mnp[p].y, fminf(u0.y, u1.y));
        }
    }

    // Plain (coalesced) store of this chunk's partial min
    float* prow = pbase + (size_t)blockIdx.y * nOwn + a_start;
#pragma unroll
    for (int p = 0; p < HP; ++p) {
        prow[threadIdx.x + (2 * p) * BLOCK]     = mnp[p].x;
        prow[threadIdx.x + (2 * p + 1) * BLOCK] = mnp[p].y;
    }
}

// Phase 2: per point, min over nchunk partials + |a|^2; weighted sum;
// one fp32 atomicAdd per block.
__global__ __launch_bounds__(256) void chamfer_finalize_kernel(
    const float* __restrict__ arr1, const float* __restrict__ arr2,
    const float* __restrict__ part, int BN, int BM, int nchunk,
    float* __restrict__ out)
{
    const int total = BN + BM;
    const float wA = 1.0f / (float)BN;
    const float wB = 1.0f / (float)BM;

    float s = 0.0f;
    for (int i = blockIdx.x * 256 + threadIdx.x; i < total; i += 256 * FBLOCKS) {
        const float* arr;
        const float* pb;
        int idx, stride;
        float w;
        if (i < BN) { arr = arr1; pb = part;                        idx = i;      stride = BN; w = wA; }
        else        { arr = arr2; pb = part + (size_t)nchunk * BN;  idx = i - BN; stride = BM; w = wB; }

        float mn = pb[idx];
        for (int c = 1; c < nchunk; ++c)
            mn = fminf(mn, pb[(size_t)c * stride + idx]);

        float x = arr[idx * 3 + 0], y = arr[idx * 3 + 1], z = arr[idx * 3 + 2];
        s += w * (mn + __builtin_fmaf(x, x, __builtin_fmaf(y, y, z * z)));
    }

    // wave64 shuffle reduce, then cross-wave via LDS
#pragma unroll
    for (int off = 32; off > 0; off >>= 1)
        s += __shfl_down(s, off, 64);

    __shared__ float wsum[4];
    int lane = threadIdx.x & 63, wv = threadIdx.x >> 6;
    if (lane == 0) wsum[wv] = s;
    __syncthreads();
    if (threadIdx.x == 0)
        atomicAdd(out, wsum[0] + wsum[1] + wsum[2] + wsum[3]);
}

extern "C" void kernel_launch(void* const* d_in, const int* in_sizes, int n_in,
                              void* d_out, int out_size, void* d_ws, size_t ws_size,
                              hipStream_t stream)
{
    const float* arr1 = (const float*)d_in[0];
    const float* arr2 = (const float*)d_in[1];
    float* out = (float*)d_out;

    const int Bb = 4;
    const int N = in_sizes[0] / (Bb * 3);   // 8192
    const int M = in_sizes[1] / (Bb * 3);   // 8192
    const int BN = Bb * N, BM = Bb * M;

    // Pick nchunk but stay inside ws_size.
    int nchunk = NCHUNK;
    while (nchunk > 4 && (size_t)(BN + BM) * (size_t)nchunk * sizeof(float) > ws_size)
        nchunk >>= 1;

    float* part = (float*)d_ws;   // [2][nchunk][32768] partial mins

    const int clen = M / nchunk;  // == N / nchunk (both 8192)
    dim3 grid(BN / (BLOCK * PPT), nchunk, 2);   // (8, nchunk, 2)
    chamfer_min_kernel<<<grid, BLOCK, clen * sizeof(float4), stream>>>(
        arr1, arr2, Bb, N, M, nchunk, part, out);

    chamfer_finalize_kernel<<<FBLOCKS, 256, 0, stream>>>(
        arr1, arr2, part, BN, BM, nchunk, out);
}

// Round 6
// 117.260 us; speedup vs baseline: 1.0096x; 1.0096x over previous
//
#include <hip/hip_runtime.h>
#include <math.h>

#define BLOCK 256
#define PPT 8            // owned points per thread -> 2048 points per block
#define NCHUNK 64        // opposing dimension split into chunks of 128
#define FBLOCKS 256      // finalize blocks

// Phase 1: for each owned point p (register-resident), scan a chunk of the
// opposing set (staged in LDS, pre-scaled to (-2x,-2y,-2z,|b|^2)) and record
// the chunk-partial min of (b^2 - 2 a.b) via a PLAIN store:
// part[dir][chunk][point].  a^2 added in finalize.
//
// R6: scalar v_fma (pk_fma is half-rate -> no gain), manual software pipeline
// on the LDS reads (prefetch j+2,j+3 while computing j,j+1) to kill the
// ds_read->use latency bubbles, and 2048 blocks / ~60 VGPR for 8 waves/SIMD.
__global__ __launch_bounds__(BLOCK) void chamfer_min_kernel(
    const float* __restrict__ arr1, const float* __restrict__ arr2,
    int Bb, int N, int M, int nchunk,
    float* __restrict__ part, float* __restrict__ out)
{
    const int dir = blockIdx.z;
    const int nA = dir ? M : N;
    const int nB = dir ? N : M;
    const float* Aptr = dir ? arr2 : arr1;   // owned points
    const float* Bptr = dir ? arr1 : arr2;   // scanned points
    const int BN = Bb * N;
    const int nOwn = Bb * nA;
    float* pbase = part + (dir ? (size_t)nchunk * BN : 0);

    // Zero the output accumulator exactly once (finalize is a later dispatch).
    if (blockIdx.x == 0 && blockIdx.y == 0 && blockIdx.z == 0 && threadIdx.x == 0)
        out[0] = 0.0f;

    const int clen = nB / nchunk;
    const int a_start = blockIdx.x * (BLOCK * PPT);  // flat index into [nOwn)
    const int batch   = a_start / nA;                // 2048 | 8192 -> exact

    extern __shared__ float4 sb[];                   // clen entries

    // Stage chunk of scanned points, pre-scaled: (-2x, -2y, -2z, |b|^2)
    {
        const float* bbase = Bptr + ((size_t)batch * nB + (size_t)blockIdx.y * clen) * 3;
        for (int i = threadIdx.x; i < clen; i += BLOCK) {
            float x = bbase[i * 3 + 0];
            float y = bbase[i * 3 + 1];
            float z = bbase[i * 3 + 2];
            sb[i] = make_float4(-2.0f * x, -2.0f * y, -2.0f * z,
                                __builtin_fmaf(x, x, __builtin_fmaf(y, y, z * z)));
        }
    }
    __syncthreads();

    // Owned points in registers (raw coords)
    float ax[PPT], ay[PPT], az[PPT], mn[PPT];
    const float* abase = Aptr + (size_t)a_start * 3;
#pragma unroll
    for (int k = 0; k < PPT; ++k) {
        int idx = threadIdx.x + k * BLOCK;
        ax[k] = abase[idx * 3 + 0];
        ay[k] = abase[idx * 3 + 1];
        az[k] = abase[idx * 3 + 2];
        mn[k] = __builtin_inff();
    }

    // Software-pipelined inner scan: compute on (c0,c1) while (n0,n1) load.
    // Per (2j, k): 6 fma + 1 min3 -> 3.5 VALU slots per pair-eval.
    float4 c0 = sb[0];
    float4 c1 = sb[1];
    for (int j = 0; j < clen - 2; j += 2) {
        float4 n0 = sb[j + 2];
        float4 n1 = sb[j + 3];
#pragma unroll
        for (int k = 0; k < PPT; ++k) {
            float u0 = __builtin_fmaf(c0.x, ax[k],
                       __builtin_fmaf(c0.y, ay[k],
                       __builtin_fmaf(c0.z, az[k], c0.w)));
            float u1 = __builtin_fmaf(c1.x, ax[k],
                       __builtin_fmaf(c1.y, ay[k],
                       __builtin_fmaf(c1.z, az[k], c1.w)));
            mn[k] = fminf(mn[k], fminf(u0, u1));
        }
        c0 = n0;
        c1 = n1;
    }
    // Epilogue: last pair
#pragma unroll
    for (int k = 0; k < PPT; ++k) {
        float u0 = __builtin_fmaf(c0.x, ax[k],
                   __builtin_fmaf(c0.y, ay[k],
                   __builtin_fmaf(c0.z, az[k], c0.w)));
        float u1 = __builtin_fmaf(c1.x, ax[k],
                   __builtin_fmaf(c1.y, ay[k],
                   __builtin_fmaf(c1.z, az[k], c1.w)));
        mn[k] = fminf(mn[k], fminf(u0, u1));
    }

    // Plain (coalesced) store of this chunk's partial min
    float* prow = pbase + (size_t)blockIdx.y * nOwn + a_start;
#pragma unroll
    for (int k = 0; k < PPT; ++k)
        prow[threadIdx.x + k * BLOCK] = mn[k];
}

// Phase 2: per point, min over nchunk partials + |a|^2; weighted sum;
// one fp32 atomicAdd per block.
__global__ __launch_bounds__(256) void chamfer_finalize_kernel(
    const float* __restrict__ arr1, const float* __restrict__ arr2,
    const float* __restrict__ part, int BN, int BM, int nchunk,
    float* __restrict__ out)
{
    const int total = BN + BM;
    const float wA = 1.0f / (float)BN;
    const float wB = 1.0f / (float)BM;

    float s = 0.0f;
    for (int i = blockIdx.x * 256 + threadIdx.x; i < total; i += 256 * FBLOCKS) {
        const float* arr;
        const float* pb;
        int idx, stride;
        float w;
        if (i < BN) { arr = arr1; pb = part;                        idx = i;      stride = BN; w = wA; }
        else        { arr = arr2; pb = part + (size_t)nchunk * BN;  idx = i - BN; stride = BM; w = wB; }

        float mn = pb[idx];
        for (int c = 1; c < nchunk; ++c)
            mn = fminf(mn, pb[(size_t)c * stride + idx]);

        float x = arr[idx * 3 + 0], y = arr[idx * 3 + 1], z = arr[idx * 3 + 2];
        s += w * (mn + __builtin_fmaf(x, x, __builtin_fmaf(y, y, z * z)));
    }

    // wave64 shuffle reduce, then cross-wave via LDS
#pragma unroll
    for (int off = 32; off > 0; off >>= 1)
        s += __shfl_down(s, off, 64);

    __shared__ float wsum[4];
    int lane = threadIdx.x & 63, wv = threadIdx.x >> 6;
    if (lane == 0) wsum[wv] = s;
    __syncthreads();
    if (threadIdx.x == 0)
        atomicAdd(out, wsum[0] + wsum[1] + wsum[2] + wsum[3]);
}

extern "C" void kernel_launch(void* const* d_in, const int* in_sizes, int n_in,
                              void* d_out, int out_size, void* d_ws, size_t ws_size,
                              hipStream_t stream)
{
    const float* arr1 = (const float*)d_in[0];
    const float* arr2 = (const float*)d_in[1];
    float* out = (float*)d_out;

    const int Bb = 4;
    const int N = in_sizes[0] / (Bb * 3);   // 8192
    const int M = in_sizes[1] / (Bb * 3);   // 8192
    const int BN = Bb * N, BM = Bb * M;

    // Pick nchunk (2048 blocks at 64) but stay inside ws_size.
    int nchunk = NCHUNK;
    while (nchunk > 4 && (size_t)(BN + BM) * (size_t)nchunk * sizeof(float) > ws_size)
        nchunk >>= 1;

    float* part = (float*)d_ws;   // [2][nchunk][32768] partial mins

    const int clen = M / nchunk;  // == N / nchunk (both 8192)
    dim3 grid(BN / (BLOCK * PPT), nchunk, 2);   // (16, nchunk, 2)
    chamfer_min_kernel<<<grid, BLOCK, clen * sizeof(float4), stream>>>(
        arr1, arr2, Bb, N, M, nchunk, part, out);

    chamfer_finalize_kernel<<<FBLOCKS, 256, 0, stream>>>(
        arr1, arr2, part, BN, BM, nchunk, out);
}

// Round 7
// 97.230 us; speedup vs baseline: 1.2176x; 1.2060x over previous
//
#include <hip/hip_runtime.h>
#include <math.h>

#define BLOCK 256
#define PPT 8               // rows per thread -> 2048 rows per block
#define RPB (BLOCK * PPT)   // 2048
#define CLEN 64             // cols per block tile
#define SPAD 257            // scmin padded stride (odd -> conflict-free reduce)
#define FBLOCKS 128

// ---- order-preserving float <-> uint key (works for negatives) ----
__device__ __forceinline__ unsigned f2key(float f) {
    unsigned b = __float_as_uint(f);
    return b ^ ((b & 0x80000000u) ? 0xFFFFFFFFu : 0x80000000u);
}
__device__ __forceinline__ float key2f(unsigned k) {
    unsigned b = k ^ ((k & 0x80000000u) ? 0x80000000u : 0xFFFFFFFFu);
    return __uint_as_float(b);
}

// Shared-d tile kernel: block = (2048 rows of array1) x (64 cols of array2)
// for one batch. Computes full d = a^2 + b^2 - 2ab ONCE per pair (fma chain
// seeded with t = a2 + b.w so both direction-constants are inside the min):
//   - row mins (dist1): register accumulators, min3 over col pairs
//   - col mins (dist2): per-thread fold over its 8 rows -> scmin[col][tid],
//     block-level reduce, then one atomicMin per col
// Partials combine across blocks via global atomicMin on order-keys
// (keys pre-set to 0xFF by a memset; R1 showed atomics at this density are free).
__global__ __launch_bounds__(BLOCK) void chamfer_tile_kernel(
    const float* __restrict__ arr1, const float* __restrict__ arr2,
    int N, int M,
    unsigned* __restrict__ rkey, unsigned* __restrict__ ckey,
    float* __restrict__ out)
{
    const int b  = blockIdx.z;
    const int r0 = blockIdx.x * RPB;     // row offset within batch
    const int c0 = blockIdx.y * CLEN;    // col offset within batch

    // Zero the output accumulator exactly once (finalize is a later dispatch).
    if (blockIdx.x == 0 && blockIdx.y == 0 && blockIdx.z == 0 && threadIdx.x == 0)
        out[0] = 0.0f;

    __shared__ float4 sb[CLEN];
    __shared__ float scmin[CLEN][SPAD];
    __shared__ float cred[4][CLEN];

    // Stage col points, prescaled: (-2x, -2y, -2z, |b|^2)
    if (threadIdx.x < CLEN) {
        const float* p = arr2 + ((size_t)b * M + c0 + threadIdx.x) * 3;
        float x = p[0], y = p[1], z = p[2];
        sb[threadIdx.x] = make_float4(-2.0f * x, -2.0f * y, -2.0f * z,
                                      __builtin_fmaf(x, x, __builtin_fmaf(y, y, z * z)));
    }
    __syncthreads();

    // Row points in registers (+ their squared norms)
    float ax[PPT], ay[PPT], az[PPT], a2[PPT], mn[PPT];
    const float* abase = arr1 + ((size_t)b * N + r0) * 3;
#pragma unroll
    for (int k = 0; k < PPT; ++k) {
        int idx = threadIdx.x + k * BLOCK;
        float x = abase[idx * 3 + 0];
        float y = abase[idx * 3 + 1];
        float z = abase[idx * 3 + 2];
        ax[k] = x; ay[k] = y; az[k] = z;
        a2[k] = __builtin_fmaf(x, x, __builtin_fmaf(y, y, z * z));
        mn[k] = __builtin_inff();
    }

    // Inner scan: 2 cols per step. Per (2j, k): 2 add + 6 fma + 1 min3(row)
    // + fold share -> ~2.75 slots per pair SERVING BOTH DIRECTIONS.
    for (int jj = 0; jj < CLEN; jj += 2) {
        float4 b0 = sb[jj];
        float4 b1 = sb[jj + 1];
        float d0a[PPT], d1a[PPT];
#pragma unroll
        for (int k = 0; k < PPT; ++k) {
            float t0 = a2[k] + b0.w;
            float t1 = a2[k] + b1.w;
            float d0 = __builtin_fmaf(b0.x, ax[k],
                       __builtin_fmaf(b0.y, ay[k],
                       __builtin_fmaf(b0.z, az[k], t0)));
            float d1 = __builtin_fmaf(b1.x, ax[k],
                       __builtin_fmaf(b1.y, ay[k],
                       __builtin_fmaf(b1.z, az[k], t1)));
            mn[k] = fminf(mn[k], fminf(d0, d1));   // row min (min3)
            d0a[k] = d0;
            d1a[k] = d1;
        }
        // Col partial: fold this thread's 8 rows for each of the 2 cols
        float cm0 = fminf(fminf(fminf(d0a[0], d0a[1]), fminf(d0a[2], d0a[3])),
                          fminf(fminf(d0a[4], d0a[5]), fminf(d0a[6], d0a[7])));
        float cm1 = fminf(fminf(fminf(d1a[0], d1a[1]), fminf(d1a[2], d1a[3])),
                          fminf(fminf(d1a[4], d1a[5]), fminf(d1a[6], d1a[7])));
        scmin[jj][threadIdx.x]     = cm0;   // conflict-free (consecutive banks)
        scmin[jj + 1][threadIdx.x] = cm1;
    }

    // Row partials -> global atomic min
    unsigned* rk = rkey + (size_t)b * N + r0;
#pragma unroll
    for (int k = 0; k < PPT; ++k)
        atomicMin(&rk[threadIdx.x + k * BLOCK], f2key(mn[k]));

    __syncthreads();

    // Col reduce: lane c of wave s reduces scmin[c][s*64 .. s*64+63]
    // bank = (c*257 + s*64 + i) % 32 = (c + i) % 32 -> conflict-free
    {
        int c = threadIdx.x & 63, s = threadIdx.x >> 6;
        float v = scmin[c][s * 64];
        for (int i = 1; i < 64; ++i)
            v = fminf(v, scmin[c][s * 64 + i]);
        cred[s][c] = v;
    }
    __syncthreads();
    if (threadIdx.x < CLEN) {
        float v = fminf(fminf(cred[0][threadIdx.x], cred[1][threadIdx.x]),
                        fminf(cred[2][threadIdx.x], cred[3][threadIdx.x]));
        atomicMin(&ckey[(size_t)b * M + c0 + threadIdx.x], f2key(v));
    }
}

// Finalize: keys already hold full d mins (a^2 and b^2 included) -> just a
// weighted sum of 64k values (0.26 MB), one atomicAdd per block.
__global__ __launch_bounds__(256) void chamfer_finalize_kernel(
    const unsigned* __restrict__ rkey, const unsigned* __restrict__ ckey,
    int BN, int BM, float* __restrict__ out)
{
    const float wA = 1.0f / (float)BN;
    const float wB = 1.0f / (float)BM;
    const int stride = 256 * FBLOCKS;

    float s = 0.0f;
    for (int i = blockIdx.x * 256 + threadIdx.x; i < BN; i += stride)
        s += wA * key2f(rkey[i]);
    for (int i = blockIdx.x * 256 + threadIdx.x; i < BM; i += stride)
        s += wB * key2f(ckey[i]);

#pragma unroll
    for (int off = 32; off > 0; off >>= 1)
        s += __shfl_down(s, off, 64);

    __shared__ float wsum[4];
    int lane = threadIdx.x & 63, wv = threadIdx.x >> 6;
    if (lane == 0) wsum[wv] = s;
    __syncthreads();
    if (threadIdx.x == 0)
        atomicAdd(out, wsum[0] + wsum[1] + wsum[2] + wsum[3]);
}

extern "C" void kernel_launch(void* const* d_in, const int* in_sizes, int n_in,
                              void* d_out, int out_size, void* d_ws, size_t ws_size,
                              hipStream_t stream)
{
    const float* arr1 = (const float*)d_in[0];
    const float* arr2 = (const float*)d_in[1];
    float* out = (float*)d_out;

    const int Bb = 4;
    const int N = in_sizes[0] / (Bb * 3);   // 8192
    const int M = in_sizes[1] / (Bb * 3);   // 8192
    const int BN = Bb * N, BM = Bb * M;

    unsigned* rkey = (unsigned*)d_ws;        // [BN]
    unsigned* ckey = rkey + BN;              // [BM]

    // Init all min-keys to 0xFFFFFFFF (max) — ws is poisoned 0xAA each launch.
    hipMemsetAsync(rkey, 0xFF, (size_t)(BN + BM) * sizeof(unsigned), stream);

    dim3 grid(N / RPB, M / CLEN, Bb);       // (4, 128, 4) = 2048 blocks
    chamfer_tile_kernel<<<grid, BLOCK, 0, stream>>>(arr1, arr2, N, M,
                                                    rkey, ckey, out);

    chamfer_finalize_kernel<<<FBLOCKS, 256, 0, stream>>>(rkey, ckey, BN, BM, out);
}

// Round 8
// 90.538 us; speedup vs baseline: 1.3076x; 1.0739x over previous
//
#include <hip/hip_runtime.h>
#include <math.h>

#define BLOCK 256
#define PPT 8               // rows per thread -> 2048 rows per block
#define RPB (BLOCK * PPT)   // 2048
#define CLEN 32             // cols per block tile (32 -> 34 KB LDS, 4 blocks/CU)
#define SPAD 257            // scmin padded stride (bank = (c+i)%32, conflict-free)
#define FBLOCKS 128

// ---- order-preserving float <-> uint key (works for negatives) ----
__device__ __forceinline__ unsigned f2key(float f) {
    unsigned b = __float_as_uint(f);
    return b ^ ((b & 0x80000000u) ? 0xFFFFFFFFu : 0x80000000u);
}
__device__ __forceinline__ float key2f(unsigned k) {
    unsigned b = k ^ ((k & 0x80000000u) ? 0x80000000u : 0xFFFFFFFFu);
    return __uint_as_float(b);
}

// Shared-d tile kernel: block = (2048 rows of array1) x (32 cols of array2)
// for one batch. Computes full d = a^2 + b^2 - 2ab ONCE per pair (fma chain
// seeded with t = a2 + b.w so both direction-constants are inside the min):
//   - row mins (dist1): register accumulators, min3 over col pairs
//   - col mins (dist2): per-thread fold over its 8 rows -> scmin[col][tid],
//     block tree-reduce, one atomicMin per col
// Cross-block combine via global atomicMin on order-keys (memset 0xFF first).
// CLEN=32 keeps LDS at 34 KB -> 4 blocks/CU (R7's 68 KB gave only 2, and the
// reduce tail stalled at 2 waves/SIMD).
__global__ __launch_bounds__(BLOCK) void chamfer_tile_kernel(
    const float* __restrict__ arr1, const float* __restrict__ arr2,
    int N, int M,
    unsigned* __restrict__ rkey, unsigned* __restrict__ ckey,
    float* __restrict__ out)
{
    const int b  = blockIdx.z;
    const int r0 = blockIdx.x * RPB;     // row offset within batch
    const int c0 = blockIdx.y * CLEN;    // col offset within batch

    // Zero the output accumulator exactly once (finalize is a later dispatch).
    if (blockIdx.x == 0 && blockIdx.y == 0 && blockIdx.z == 0 && threadIdx.x == 0)
        out[0] = 0.0f;

    __shared__ float4 sb[CLEN];
    __shared__ float scmin[CLEN][SPAD];
    __shared__ float cred[8][CLEN];

    // Stage col points, prescaled: (-2x, -2y, -2z, |b|^2)
    if (threadIdx.x < CLEN) {
        const float* p = arr2 + ((size_t)b * M + c0 + threadIdx.x) * 3;
        float x = p[0], y = p[1], z = p[2];
        sb[threadIdx.x] = make_float4(-2.0f * x, -2.0f * y, -2.0f * z,
                                      __builtin_fmaf(x, x, __builtin_fmaf(y, y, z * z)));
    }
    __syncthreads();

    // Row points in registers (+ their squared norms)
    float ax[PPT], ay[PPT], az[PPT], a2[PPT], mn[PPT];
    const float* abase = arr1 + ((size_t)b * N + r0) * 3;
#pragma unroll
    for (int k = 0; k < PPT; ++k) {
        int idx = threadIdx.x + k * BLOCK;
        float x = abase[idx * 3 + 0];
        float y = abase[idx * 3 + 1];
        float z = abase[idx * 3 + 2];
        ax[k] = x; ay[k] = y; az[k] = z;
        a2[k] = __builtin_fmaf(x, x, __builtin_fmaf(y, y, z * z));
        mn[k] = __builtin_inff();
    }

    // Inner scan: 2 cols per step. Per (2j, k): 2 add + 6 fma + 1 min3(row)
    // + col-fold share -> ~5.4 slots per pair SERVING BOTH DIRECTIONS.
    for (int jj = 0; jj < CLEN; jj += 2) {
        float4 b0 = sb[jj];
        float4 b1 = sb[jj + 1];
        float d0a[PPT], d1a[PPT];
#pragma unroll
        for (int k = 0; k < PPT; ++k) {
            float t0 = a2[k] + b0.w;
            float t1 = a2[k] + b1.w;
            float d0 = __builtin_fmaf(b0.x, ax[k],
                       __builtin_fmaf(b0.y, ay[k],
                       __builtin_fmaf(b0.z, az[k], t0)));
            float d1 = __builtin_fmaf(b1.x, ax[k],
                       __builtin_fmaf(b1.y, ay[k],
                       __builtin_fmaf(b1.z, az[k], t1)));
            mn[k] = fminf(mn[k], fminf(d0, d1));   // row min (min3)
            d0a[k] = d0;
            d1a[k] = d1;
        }
        // Col partial: fold this thread's 8 rows for each of the 2 cols
        float cm0 = fminf(fminf(fminf(d0a[0], d0a[1]), fminf(d0a[2], d0a[3])),
                          fminf(fminf(d0a[4], d0a[5]), fminf(d0a[6], d0a[7])));
        float cm1 = fminf(fminf(fminf(d1a[0], d1a[1]), fminf(d1a[2], d1a[3])),
                          fminf(fminf(d1a[4], d1a[5]), fminf(d1a[6], d1a[7])));
        scmin[jj][threadIdx.x]     = cm0;   // bank (jj+tid)%32: 2-way max, free
        scmin[jj + 1][threadIdx.x] = cm1;
    }

    // Row partials -> global atomic min
    unsigned* rk = rkey + (size_t)b * N + r0;
#pragma unroll
    for (int k = 0; k < PPT; ++k)
        atomicMin(&rk[threadIdx.x + k * BLOCK], f2key(mn[k]));

    __syncthreads();

    // Col reduce stage 1: thread (c = tid&31, s = tid>>5) tree-reduces
    // scmin[c][s*32 .. s*32+31].  bank = (c+i)%32 -> <=2-way (free).
    {
        int c = threadIdx.x & 31, s = threadIdx.x >> 5;
        const float* row = &scmin[c][s * 32];
        float v0 = row[0], v1 = row[1];
#pragma unroll
        for (int i = 2; i < 32; i += 2) {
            v0 = fminf(v0, row[i]);
            v1 = fminf(v1, row[i + 1]);
        }
        cred[s][c] = fminf(v0, v1);
    }
    __syncthreads();
    // Stage 2: 32 threads fold the 8 segment partials, one atomic per col.
    if (threadIdx.x < CLEN) {
        float v = fminf(fminf(fminf(cred[0][threadIdx.x], cred[1][threadIdx.x]),
                              fminf(cred[2][threadIdx.x], cred[3][threadIdx.x])),
                        fminf(fminf(cred[4][threadIdx.x], cred[5][threadIdx.x]),
                              fminf(cred[6][threadIdx.x], cred[7][threadIdx.x])));
        atomicMin(&ckey[(size_t)b * M + c0 + threadIdx.x], f2key(v));
    }
}

// Finalize: keys already hold full d mins (a^2 and b^2 included) -> just a
// weighted sum of 64k values (0.26 MB), one atomicAdd per block.
__global__ __launch_bounds__(256) void chamfer_finalize_kernel(
    const unsigned* __restrict__ rkey, const unsigned* __restrict__ ckey,
    int BN, int BM, float* __restrict__ out)
{
    const float wA = 1.0f / (float)BN;
    const float wB = 1.0f / (float)BM;
    const int stride = 256 * FBLOCKS;

    float s = 0.0f;
    for (int i = blockIdx.x * 256 + threadIdx.x; i < BN; i += stride)
        s += wA * key2f(rkey[i]);
    for (int i = blockIdx.x * 256 + threadIdx.x; i < BM; i += stride)
        s += wB * key2f(ckey[i]);

#pragma unroll
    for (int off = 32; off > 0; off >>= 1)
        s += __shfl_down(s, off, 64);

    __shared__ float wsum[4];
    int lane = threadIdx.x & 63, wv = threadIdx.x >> 6;
    if (lane == 0) wsum[wv] = s;
    __syncthreads();
    if (threadIdx.x == 0)
        atomicAdd(out, wsum[0] + wsum[1] + wsum[2] + wsum[3]);
}

extern "C" void kernel_launch(void* const* d_in, const int* in_sizes, int n_in,
                              void* d_out, int out_size, void* d_ws, size_t ws_size,
                              hipStream_t stream)
{
    const float* arr1 = (const float*)d_in[0];
    const float* arr2 = (const float*)d_in[1];
    float* out = (float*)d_out;

    const int Bb = 4;
    const int N = in_sizes[0] / (Bb * 3);   // 8192
    const int M = in_sizes[1] / (Bb * 3);   // 8192
    const int BN = Bb * N, BM = Bb * M;

    unsigned* rkey = (unsigned*)d_ws;        // [BN]
    unsigned* ckey = rkey + BN;              // [BM]

    // Init all min-keys to 0xFFFFFFFF (max) — ws is poisoned 0xAA each launch.
    hipMemsetAsync(rkey, 0xFF, (size_t)(BN + BM) * sizeof(unsigned), stream);

    dim3 grid(N / RPB, M / CLEN, Bb);       // (4, 256, 4) = 4096 blocks
    chamfer_tile_kernel<<<grid, BLOCK, 0, stream>>>(arr1, arr2, N, M,
                                                    rkey, ckey, out);

    chamfer_finalize_kernel<<<FBLOCKS, 256, 0, stream>>>(rkey, ckey, BN, BM, out);
}

// Round 9
// 88.646 us; speedup vs baseline: 1.3355x; 1.0213x over previous
//
#include <hip/hip_runtime.h>
#include <math.h>

#define BLOCK 256
#define PPT 8               // rows per thread -> 2048 rows per block
#define RPB (BLOCK * PPT)   // 2048
#define CLEN 32             // cols per block tile (34 KB LDS -> 4 blocks/CU)
#define SPAD 257            // scmin padded stride (bank = (c+i)%32, conflict-free)
#define FBLOCKS 128

// ---- order-preserving float <-> uint key (works for negatives) ----
__device__ __forceinline__ unsigned f2key(float f) {
    unsigned b = __float_as_uint(f);
    return b ^ ((b & 0x80000000u) ? 0xFFFFFFFFu : 0x80000000u);
}
__device__ __forceinline__ float key2f(unsigned k) {
    unsigned b = k ^ ((k & 0x80000000u) ? 0x80000000u : 0xFFFFFFFFu);
    return __uint_as_float(b);
}
__device__ __forceinline__ float min3f(float a, float b, float c) {
    return fminf(fminf(a, b), c);   // -> v_min3_f32
}

// Shared-d tile kernel: block = (2048 rows of array1) x (32 cols of array2)
// for one batch. Computes full d = a^2 + b^2 - 2ab ONCE per pair (fma chain
// seeded with t = a2 + b.w so both direction-constants are inside the min):
//   - row mins (dist1): register accumulators, min3 over col pairs
//   - col mins (dist2): per-thread min3-fold over its 8 rows -> scmin[col][tid],
//     block tree-reduce, one atomicMin per col
// Cross-block combine via global atomicMin on order-keys (memset 0xFF first).
// jj loop fully unrolled (16 iters) so the scheduler can hoist the independent
// ds_read_b128s ahead of the fma stream (rolled loop stalled at ~50% issue).
__global__ __launch_bounds__(BLOCK, 4) void chamfer_tile_kernel(
    const float* __restrict__ arr1, const float* __restrict__ arr2,
    int N, int M,
    unsigned* __restrict__ rkey, unsigned* __restrict__ ckey,
    float* __restrict__ out)
{
    const int b  = blockIdx.z;
    const int r0 = blockIdx.x * RPB;     // row offset within batch
    const int c0 = blockIdx.y * CLEN;    // col offset within batch

    // Zero the output accumulator exactly once (finalize is a later dispatch).
    if (blockIdx.x == 0 && blockIdx.y == 0 && blockIdx.z == 0 && threadIdx.x == 0)
        out[0] = 0.0f;

    __shared__ float4 sb[CLEN];
    __shared__ float scmin[CLEN][SPAD];
    __shared__ float cred[8][CLEN];

    // Stage col points, prescaled: (-2x, -2y, -2z, |b|^2)
    if (threadIdx.x < CLEN) {
        const float* p = arr2 + ((size_t)b * M + c0 + threadIdx.x) * 3;
        float x = p[0], y = p[1], z = p[2];
        sb[threadIdx.x] = make_float4(-2.0f * x, -2.0f * y, -2.0f * z,
                                      __builtin_fmaf(x, x, __builtin_fmaf(y, y, z * z)));
    }
    __syncthreads();

    // Row points in registers (+ their squared norms)
    float ax[PPT], ay[PPT], az[PPT], a2[PPT], mn[PPT];
    const float* abase = arr1 + ((size_t)b * N + r0) * 3;
#pragma unroll
    for (int k = 0; k < PPT; ++k) {
        int idx = threadIdx.x + k * BLOCK;
        float x = abase[idx * 3 + 0];
        float y = abase[idx * 3 + 1];
        float z = abase[idx * 3 + 2];
        ax[k] = x; ay[k] = y; az[k] = z;
        a2[k] = __builtin_fmaf(x, x, __builtin_fmaf(y, y, z * z));
        mn[k] = __builtin_inff();
    }

    // Inner scan: 2 cols per step, fully unrolled. Per (2j, k): 2 add + 6 fma
    // + 1 min3(row); col fold 2x4 min3 -> 5.0 slots per pair, both directions.
#pragma unroll
    for (int jj = 0; jj < CLEN; jj += 2) {
        float4 b0 = sb[jj];
        float4 b1 = sb[jj + 1];
        float d0a[PPT], d1a[PPT];
#pragma unroll
        for (int k = 0; k < PPT; ++k) {
            float t0 = a2[k] + b0.w;
            float t1 = a2[k] + b1.w;
            float d0 = __builtin_fmaf(b0.x, ax[k],
                       __builtin_fmaf(b0.y, ay[k],
                       __builtin_fmaf(b0.z, az[k], t0)));
            float d1 = __builtin_fmaf(b1.x, ax[k],
                       __builtin_fmaf(b1.y, ay[k],
                       __builtin_fmaf(b1.z, az[k], t1)));
            mn[k] = min3f(mn[k], d0, d1);   // row min
            d0a[k] = d0;
            d1a[k] = d1;
        }
        // Col partial: min3-fold this thread's 8 rows for each of the 2 cols
        float cm0 = fminf(min3f(min3f(min3f(d0a[0], d0a[1], d0a[2]),
                                      d0a[3], d0a[4]),
                                d0a[5], d0a[6]),
                          d0a[7]);
        float cm1 = fminf(min3f(min3f(min3f(d1a[0], d1a[1], d1a[2]),
                                      d1a[3], d1a[4]),
                                d1a[5], d1a[6]),
                          d1a[7]);
        scmin[jj][threadIdx.x]     = cm0;   // bank (jj+tid)%32: 2-way max, free
        scmin[jj + 1][threadIdx.x] = cm1;
    }

    // Row partials -> global atomic min
    unsigned* rk = rkey + (size_t)b * N + r0;
#pragma unroll
    for (int k = 0; k < PPT; ++k)
        atomicMin(&rk[threadIdx.x + k * BLOCK], f2key(mn[k]));

    __syncthreads();

    // Col reduce stage 1: thread (c = tid&31, s = tid>>5) tree-reduces
    // scmin[c][s*32 .. s*32+31].  bank = (c+i)%32 -> <=2-way (free).
    {
        int c = threadIdx.x & 31, s = threadIdx.x >> 5;
        const float* row = &scmin[c][s * 32];
        float v0 = row[0], v1 = row[1];
#pragma unroll
        for (int i = 2; i < 32; i += 2) {
            v0 = fminf(v0, row[i]);
            v1 = fminf(v1, row[i + 1]);
        }
        cred[s][c] = fminf(v0, v1);
    }
    __syncthreads();
    // Stage 2: 32 threads fold the 8 segment partials, one atomic per col.
    if (threadIdx.x < CLEN) {
        float v = fminf(min3f(min3f(min3f(cred[0][threadIdx.x],
                                          cred[1][threadIdx.x],
                                          cred[2][threadIdx.x]),
                                    cred[3][threadIdx.x],
                                    cred[4][threadIdx.x]),
                              cred[5][threadIdx.x],
                              cred[6][threadIdx.x]),
                        cred[7][threadIdx.x]);
        atomicMin(&ckey[(size_t)b * M + c0 + threadIdx.x], f2key(v));
    }
}

// Finalize: keys already hold full d mins (a^2 and b^2 included) -> just a
// weighted sum of 64k values (0.26 MB), one atomicAdd per block.
__global__ __launch_bounds__(256) void chamfer_finalize_kernel(
    const unsigned* __restrict__ rkey, const unsigned* __restrict__ ckey,
    int BN, int BM, float* __restrict__ out)
{
    const float wA = 1.0f / (float)BN;
    const float wB = 1.0f / (float)BM;
    const int stride = 256 * FBLOCKS;

    float s = 0.0f;
    for (int i = blockIdx.x * 256 + threadIdx.x; i < BN; i += stride)
        s += wA * key2f(rkey[i]);
    for (int i = blockIdx.x * 256 + threadIdx.x; i < BM; i += stride)
        s += wB * key2f(ckey[i]);

#pragma unroll
    for (int off = 32; off > 0; off >>= 1)
        s += __shfl_down(s, off, 64);

    __shared__ float wsum[4];
    int lane = threadIdx.x & 63, wv = threadIdx.x >> 6;
    if (lane == 0) wsum[wv] = s;
    __syncthreads();
    if (threadIdx.x == 0)
        atomicAdd(out, wsum[0] + wsum[1] + wsum[2] + wsum[3]);
}

extern "C" void kernel_launch(void* const* d_in, const int* in_sizes, int n_in,
                              void* d_out, int out_size, void* d_ws, size_t ws_size,
                              hipStream_t stream)
{
    const float* arr1 = (const float*)d_in[0];
    const float* arr2 = (const float*)d_in[1];
    float* out = (float*)d_out;

    const int Bb = 4;
    const int N = in_sizes[0] / (Bb * 3);   // 8192
    const int M = in_sizes[1] / (Bb * 3);   // 8192
    const int BN = Bb * N, BM = Bb * M;

    unsigned* rkey = (unsigned*)d_ws;        // [BN]
    unsigned* ckey = rkey + BN;              // [BM]

    // Init all min-keys to 0xFFFFFFFF (max) — ws is poisoned 0xAA each launch.
    hipMemsetAsync(rkey, 0xFF, (size_t)(BN + BM) * sizeof(unsigned), stream);

    dim3 grid(N / RPB, M / CLEN, Bb);       // (4, 256, 4) = 4096 blocks
    chamfer_tile_kernel<<<grid, BLOCK, 0, stream>>>(arr1, arr2, N, M,
                                                    rkey, ckey, out);

    chamfer_finalize_kernel<<<FBLOCKS, 256, 0, stream>>>(rkey, ckey, BN, BM, out);
}